// Round 3
// baseline (104.586 us; speedup 1.0000x reference)
//
#include <hip/hip_runtime.h>

typedef float v4f __attribute__((ext_vector_type(4)));
typedef int   v4i __attribute__((ext_vector_type(4)));

// Phase 1: per-node dot products s[n] = x[n]·att[0:128], t[n] = x[n]·att[128:256]
// One wave handles 4 nodes (512 contiguous floats = 64 lanes × 2 float4 loads).
// Two independent 16B loads per lane -> 2x bytes in flight for latency hiding.
__global__ __launch_bounds__(256) void node_dots_kernel(
    const float* __restrict__ x, const float* __restrict__ att,
    float* __restrict__ s, float* __restrict__ t, int n_nodes) {
  int wave = (blockIdx.x * blockDim.x + threadIdx.x) >> 6;
  int lane = threadIdx.x & 63;
  int wl   = lane & 31;   // position within half-wave (one node = 32 lanes)
  int half = lane >> 5;

  int node0 = wave * 4 + half;      // first pair:  nodes 4w, 4w+1
  int node1 = node0 + 2;            // second pair: nodes 4w+2, 4w+3
  if (node0 >= n_nodes) return;

  const v4f* a4 = (const v4f*)att;
  v4f ws = a4[wl];                  // att[0:128]   (w_src)
  v4f wt = a4[32 + wl];             // att[128:256] (w_tgt)

  const v4f* x4 = (const v4f*)x + (size_t)wave * 128 + lane;
  // Streaming, never-reused reads: nontemporal to avoid evicting s/t from L2.
  v4f v0 = __builtin_nontemporal_load(x4);
  v4f v1 = {0.f, 0.f, 0.f, 0.f};
  bool have1 = (node1 < n_nodes);
  if (have1) v1 = __builtin_nontemporal_load(x4 + 64);

  float ps0 = v0.x * ws.x + v0.y * ws.y + v0.z * ws.z + v0.w * ws.w;
  float pt0 = v0.x * wt.x + v0.y * wt.y + v0.z * wt.z + v0.w * wt.w;
  float ps1 = v1.x * ws.x + v1.y * ws.y + v1.z * ws.z + v1.w * ws.w;
  float pt1 = v1.x * wt.x + v1.y * wt.y + v1.z * wt.z + v1.w * wt.w;

  // Half-wave (32-lane) tree reduction; lanes with wl==0 hold the sums.
  #pragma unroll
  for (int off = 16; off; off >>= 1) {
    ps0 += __shfl_down(ps0, off);
    pt0 += __shfl_down(pt0, off);
    ps1 += __shfl_down(ps1, off);
    pt1 += __shfl_down(pt1, off);
  }
  if (wl == 0) {
    s[node0] = ps0;
    t[node0] = pt0;
    if (have1) {
      s[node1] = ps1;
      t[node1] = pt1;
    }
  }
}

// Phase 2: out[e] = relu(s[src[e]] + t[tgt[e]]), 4 edges per thread.
// s/t total 800 KB -> L2-resident; indices & output fully coalesced 16B/lane.
__global__ __launch_bounds__(256) void edge_signal_kernel(
    const int* __restrict__ src, const int* __restrict__ tgt,
    const float* __restrict__ s, const float* __restrict__ t,
    float* __restrict__ out, int n_edges) {
  int i = blockIdx.x * blockDim.x + threadIdx.x;
  int n4 = n_edges >> 2;
  if (i < n4) {
    v4i is = __builtin_nontemporal_load((const v4i*)src + i);
    v4i it = __builtin_nontemporal_load((const v4i*)tgt + i);
    v4f r;
    r.x = s[is.x] + t[it.x];
    r.y = s[is.y] + t[it.y];
    r.z = s[is.z] + t[it.z];
    r.w = s[is.w] + t[it.w];
    r.x = r.x > 0.f ? r.x : 0.f;
    r.y = r.y > 0.f ? r.y : 0.f;
    r.z = r.z > 0.f ? r.z : 0.f;
    r.w = r.w > 0.f ? r.w : 0.f;
    // Write-once output: nontemporal keeps s/t lines resident in L2.
    __builtin_nontemporal_store(r, (v4f*)out + i);
  } else if (i == n4) {
    // Scalar tail (n_edges % 4 elements) handled by one thread.
    for (int e = n4 * 4; e < n_edges; ++e) {
      float v = s[src[e]] + t[tgt[e]];
      out[e] = v > 0.f ? v : 0.f;
    }
  }
}

extern "C" void kernel_launch(void* const* d_in, const int* in_sizes, int n_in,
                              void* d_out, int out_size, void* d_ws, size_t ws_size,
                              hipStream_t stream) {
  const float* x_0 = (const float*)d_in[0];
  const int*   src = (const int*)d_in[1];
  const int*   tgt = (const int*)d_in[2];
  const float* att = (const float*)d_in[3];
  float* out = (float*)d_out;

  const int C = 128;
  int n_nodes = in_sizes[0] / C;   // 100000
  int n_edges = in_sizes[1];       // 800000

  float* s = (float*)d_ws;         // n_nodes floats
  float* t = s + n_nodes;          // n_nodes floats

  // Phase 1: 4 nodes per wave, 4 waves per block -> 16 nodes per block.
  int n_waves = (n_nodes + 3) / 4;
  int grid1 = (n_waves + 3) / 4;
  node_dots_kernel<<<grid1, 256, 0, stream>>>(x_0, att, s, t, n_nodes);

  // Phase 2: 4 edges per thread (+1 tail thread).
  int n_thr = n_edges / 4 + 1;
  int grid2 = (n_thr + 255) / 256;
  edge_signal_kernel<<<grid2, 256, 0, stream>>>(src, tgt, s, t, out, n_edges);
}